// Round 1
// baseline (645.079 us; speedup 1.0000x reference)
//
#include <hip/hip_runtime.h>
#include <hip/hip_bf16.h>

// ---------------------------------------------------------------------------
// EdgeFtLayer fused kernel for MI355X (gfx950).  Round 4.
//
// Changes vs round 3 (300us fused, 7 barriers, 33% occ, latency-bound):
//   * A-tile gather now uses global_load_lds width=16 async DMA into DENSE
//     LDS regions.  Bank conflicts avoided by XOR-swizzling the per-lane
//     GLOBAL source address (LDS dest stays lane-linear, as HW requires);
//     readers apply the same XOR.  edge_attr stays f32 in LDS, converted to
//     bf16 at fragment build.
//   * The two red-LDS segmented-reduction passes (4 barriers + 64KB LDS
//     round trips) are replaced by an in-register segmented reduce: each
//     lane owns 4 contiguous sorted-dst rows per m-tile (MFMA C layout),
//     sums ex / ex*msg along its chunk, atomics at run boundaries.
//   * Barriers per block: 7 -> 2.
// ---------------------------------------------------------------------------

typedef float  f32x4   __attribute__((ext_vector_type(4)));
typedef __bf16 bf16x8  __attribute__((ext_vector_type(8)));
typedef unsigned short ushort8_t __attribute__((ext_vector_type(8)));

__device__ __forceinline__ unsigned short f2bf(float f) {
  unsigned int u = __float_as_uint(f);
  return (unsigned short)((u + 0x7FFFu + ((u >> 16) & 1u)) >> 16);
}

__device__ __forceinline__ void store_bf4(unsigned short* p, float4 v) {
  ushort4 u;
  u.x = f2bf(v.x); u.y = f2bf(v.y); u.z = f2bf(v.z); u.w = f2bf(v.w);
  *(ushort4*)p = u;
}

// async 16B global -> LDS (dest = wave-uniform base + lane*16)
__device__ __forceinline__ void async16(void* lds, const void* g) {
  __builtin_amdgcn_global_load_lds(
      (const __attribute__((address_space(1))) unsigned int*)g,
      (__attribute__((address_space(3))) unsigned int*)lds, 16, 0, 0);
}

// ---------------------------------------------------------------------------
__global__ void prep_b_kernel(const float* __restrict__ Wa,
                              const float* __restrict__ Wt,
                              const float* __restrict__ We,
                              const float* __restrict__ Wee,
                              unsigned short* __restrict__ Bp) {
  int pe = blockIdx.x * 256 + threadIdx.x;          // 0 .. 102399
  int j    = pe & 7;
  int lane = (pe >> 3) & 63;
  int kt   = (pe >> 9) % 10;
  int nt   = pe / 5120;
  int k = kt * 32 + ((lane >> 4) << 3) + j;
  int n = nt * 16 + (lane & 15);
  float v;
  if (n < 128) {
    v = Wa[k * 128 + n];
  } else if (n < 256) {
    v = Wt[k * 128 + (n - 128)];
  } else {
    int c = n - 256;
    if (k < 128)      v = We[k * 64 + c];
    else if (k < 192) v = Wee[(k - 128) * 64 + c];
    else              v = We[(k - 192) * 64 + c];
  }
  Bp[pe] = f2bf(v);
}

// --------------------------- x -> bf16 pre-convert --------------------------
__global__ void xbf16_kernel(const float* __restrict__ x,
                             unsigned short* __restrict__ xb, int total4) {
  int i = blockIdx.x * 256 + threadIdx.x;
  if (i < total4) {
    float4 v = ((const float4*)x)[i];
    store_bf4(&xb[(size_t)i * 4], v);
  }
}

// --------------------------- counting sort by dst ---------------------------
__global__ void hist_kernel(const int* __restrict__ ei, int* __restrict__ cnt,
                            int E) {
  int e = blockIdx.x * 256 + threadIdx.x;
  if (e < E) atomicAdd(&cnt[ei[E + e]], 1);
}

__global__ void scan1_kernel(const int* __restrict__ cnt,
                             int* __restrict__ bsum, int n) {
  __shared__ int ls[256];
  int t = threadIdx.x;
  int i = blockIdx.x * 256 + t;
  ls[t] = (i < n) ? cnt[i] : 0;
  __syncthreads();
  for (int off = 128; off > 0; off >>= 1) {
    if (t < off) ls[t] += ls[t + off];
    __syncthreads();
  }
  if (t == 0) bsum[blockIdx.x] = ls[0];
}

__global__ void scan2_kernel(int* __restrict__ bsum, int nb) {
  __shared__ int ls[256];
  int t = threadIdx.x;
  int v = (t < nb) ? bsum[t] : 0;
  ls[t] = v;
  __syncthreads();
  for (int off = 1; off < 256; off <<= 1) {
    int u = (t >= off) ? ls[t - off] : 0;
    __syncthreads();
    ls[t] += u;
    __syncthreads();
  }
  if (t < nb) bsum[t] = ls[t] - v;   // exclusive
}

__global__ void scan3_kernel(const int* __restrict__ cnt,
                             const int* __restrict__ bsum,
                             int* __restrict__ cur, int n) {
  __shared__ int ls[256];
  int t = threadIdx.x;
  int i = blockIdx.x * 256 + t;
  int v = (i < n) ? cnt[i] : 0;
  ls[t] = v;
  __syncthreads();
  for (int off = 1; off < 256; off <<= 1) {
    int u = (t >= off) ? ls[t - off] : 0;
    __syncthreads();
    ls[t] += u;
    __syncthreads();
  }
  if (i < n) cur[i] = ls[t] - v + bsum[blockIdx.x];
}

__global__ void scatter_kernel(const int* __restrict__ ei, int* __restrict__ cur,
                               int* __restrict__ eid_s, int* __restrict__ src_s,
                               int* __restrict__ dst_s, int E) {
  int e = blockIdx.x * 256 + threadIdx.x;
  if (e < E) {
    int s = ei[e];
    int d = ei[E + e];
    int pos = atomicAdd(&cur[d], 1);
    eid_s[pos] = e;
    src_s[pos] = s;
    dst_s[pos] = d;
  }
}

// ---------------------------------------------------------------------------
// Fused gather + GEMM + register segmented-reduction epilogue.
// 64 sorted edges / block, 4 waves; wave w owns n-tiles {w, w+4, w+8, w+12, w+16}.
// ---------------------------------------------------------------------------
__global__ __launch_bounds__(256, 2) void fused_edge_kernel(
    const unsigned short* __restrict__ xb,   // bf16 x, [N,128]
    const float* __restrict__ ea,            // f32 edge_attr, [E,64]
    const int*   __restrict__ eid_s,
    const int*   __restrict__ src_s,
    const int*   __restrict__ dst_s,
    const unsigned short* __restrict__ Bp,
    float* __restrict__ num,
    float* __restrict__ den,
    float* __restrict__ out_e,
    const float* __restrict__ a_prelu,
    int E) {
  // dense LDS regions, chunk-swizzled via pre-swizzled global source addrs
  __shared__ __align__(16) unsigned short At_dst[64 * 128];  // 16 KB bf16
  __shared__ __align__(16) unsigned short At_src[64 * 128];  // 16 KB bf16
  __shared__ __align__(16) float          Aea[64 * 64];      // 16 KB f32
  __shared__ int s_src[64];
  __shared__ int s_dst[64];
  __shared__ int s_eid[64];

  const int tid = threadIdx.x;
  const int eb  = blockIdx.x * 64;
  const int nvalid = min(64, E - eb);

  if (tid < 64) {
    int e = 0, s = 0, d = 0;
    if (tid < nvalid) {
      e = eid_s[eb + tid];
      s = src_s[eb + tid];
      d = dst_s[eb + tid];
    }
    s_eid[tid] = e;
    s_src[tid] = s;
    s_dst[tid] = d;
  }
  __syncthreads();

  const int w  = tid >> 6;
  const int l  = tid & 63;
  const int g4 = l >> 4;          // which 16-lane quarter
  const int j  = l & 15;          // dest chunk within row

  // ---- async gather: 12 global_load_lds issues per wave -------------------
  // instr t covers rows [w*16 + t*4, +4); lane writes LDS base + l*16.
  // LDS slot jj of row r holds global 16B-chunk (jj ^ (r&7)).
  #pragma unroll
  for (int t = 0; t < 4; ++t) {
    int row = w * 16 + t * 4 + g4;
    int cD  = j ^ (row & 7);             // swizzled global chunk
    int nd  = s_dst[row];
    int ns  = s_src[row];
    int ee  = s_eid[row];
    async16(&At_dst[(w * 16 + t * 4) * 128], xb + (size_t)nd * 128 + cD * 8);
    async16(&At_src[(w * 16 + t * 4) * 128], xb + (size_t)ns * 128 + cD * 8);
    async16(&Aea   [(w * 16 + t * 4) * 64 ], ea + (size_t)ee * 64  + cD * 4);
  }
  __syncthreads();   // drains vmcnt(0): DMA complete

  const int lrow = l & 15;

  f32x4 acc[4][5];
  #pragma unroll
  for (int mt = 0; mt < 4; ++mt)
    #pragma unroll
    for (int i = 0; i < 5; ++i)
      acc[mt][i] = (f32x4){0.f, 0.f, 0.f, 0.f};

  #pragma unroll
  for (int kc = 0; kc < 10; ++kc) {
    bf16x8 av[4];
    #pragma unroll
    for (int mt = 0; mt < 4; ++mt) {
      int row = mt * 16 + lrow;
      int sw  = row & 7;
      ushort8_t u;
      if (kc < 4) {                      // x[dst] part, k-cols [0,128)
        int c = kc * 4 + g4;
        u = *(const ushort8_t*)&At_dst[row * 128 + ((c ^ sw) << 3)];
      } else if (kc < 6) {               // edge_attr part, k-cols [128,192)
        int c0 = (kc - 4) * 8 + g4 * 2;  // even 16B-chunk index
        float4 f0 = *(const float4*)&Aea[row * 64 + (((c0    ) ^ sw) << 2)];
        float4 f1 = *(const float4*)&Aea[row * 64 + (((c0 + 1) ^ sw) << 2)];
        u[0] = f2bf(f0.x); u[1] = f2bf(f0.y); u[2] = f2bf(f0.z); u[3] = f2bf(f0.w);
        u[4] = f2bf(f1.x); u[5] = f2bf(f1.y); u[6] = f2bf(f1.z); u[7] = f2bf(f1.w);
      } else {                           // x[src] part, k-cols [192,320)
        int c = (kc - 6) * 4 + g4;
        u = *(const ushort8_t*)&At_src[row * 128 + ((c ^ sw) << 3)];
      }
      av[mt] = __builtin_bit_cast(bf16x8, u);
    }
    #pragma unroll
    for (int i = 0; i < 5; ++i) {
      const int nt = w + 4 * i;
      ushort8_t ub = *(const ushort8_t*)&Bp[(((nt * 10 + kc) * 64) + l) * 8];
      bf16x8 bv = __builtin_bit_cast(bf16x8, ub);
      #pragma unroll
      for (int mt = 0; mt < 4; ++mt)
        acc[mt][i] = __builtin_amdgcn_mfma_f32_16x16x32_bf16(av[mt], bv, acc[mt][i], 0, 0, 0);
    }
  }

  // ------------------- epilogue (no barriers) -------------------
  // C layout: row = (lane>>4)*4 + reg, col = lane&15
  const float slope = a_prelu[0];
  const int rbase = g4 << 2;
  const int ccol  = l & 15;

  // new_e_feat (acc tile i=4 is global n-tile w+16 -> e-col = w*16 + ccol)
  #pragma unroll
  for (int mt = 0; mt < 4; ++mt) {
    const int m0 = mt * 16 + rbase;
    #pragma unroll
    for (int r = 0; r < 4; ++r) {
      int m = m0 + r;
      if (m < nvalid)
        out_e[(size_t)s_eid[m] * 64 + w * 16 + ccol] = acc[mt][4][r];
    }
  }

  // in-register segmented reduction over sorted-dst runs.
  // Each lane owns rows [m0, m0+4) of its m-tile for column c; runs are
  // contiguous, so accumulate and flush an atomic at chunk end / run end.
  #pragma unroll
  for (int mt = 0; mt < 4; ++mt) {
    const int m0 = mt * 16 + rbase;
    #pragma unroll
    for (int i2 = 0; i2 < 2; ++i2) {
      const int c = (w + 4 * i2) * 16 + ccol;
      float sn = 0.f, sd = 0.f;
      #pragma unroll
      for (int r = 0; r < 4; ++r) {
        int m = m0 + r;
        if (m < nvalid) {
          float lg = acc[mt][i2][r];
          float e_ = __expf(lg >= 0.f ? lg : slope * lg);
          sn += e_ * acc[mt][i2 + 2][r];
          sd += e_;
          bool flush = (r == 3) || (m == nvalid - 1) ||
                       (s_dst[m + 1] != s_dst[m]);
          if (flush) {
            int d = s_dst[m];
            unsafeAtomicAdd(&num[(size_t)d * 128 + c], sn);
            unsafeAtomicAdd(&den[(size_t)d * 128 + c], sd);
            sn = 0.f;
            sd = 0.f;
          }
        }
      }
    }
  }
}

// ---------------------------------------------------------------------------
__global__ void finalize_kernel(const float* __restrict__ num,
                                const float* __restrict__ den,
                                const float* __restrict__ bT,
                                float* __restrict__ out_x,
                                int total) {
  int i = blockIdx.x * 256 + threadIdx.x;
  if (i < total)
    out_x[i] = num[i] / (den[i] + 1e-16f) + bT[i & 127];
}

extern "C" void kernel_launch(void* const* d_in, const int* in_sizes, int n_in,
                              void* d_out, int out_size, void* d_ws, size_t ws_size,
                              hipStream_t stream) {
  const float* x   = (const float*)d_in[0];
  const int*   ei  = (const int*)d_in[1];
  const float* ea  = (const float*)d_in[2];
  const float* Wa  = (const float*)d_in[3];
  const float* Wt  = (const float*)d_in[4];
  const float* bT  = (const float*)d_in[5];
  const float* We  = (const float*)d_in[6];
  const float* Wee = (const float*)d_in[7];
  const float* ap  = (const float*)d_in[8];

  const int N = in_sizes[0] / 128;          // 50000
  const int E = in_sizes[1] / 2;            // 500000
  const int NB = (N + 255) / 256;           // 196 scan blocks

  // workspace layout (byte offsets)
  char* ws = (char*)d_ws;
  unsigned short* Bp = (unsigned short*)ws;                       // 204,800
  float* num = (float*)(ws + 204800);                             // 25.6 MB
  float* den = num + (size_t)N * 128;                             // 25.6 MB
  int* cnt   = (int*)(ws + 204800 + (size_t)N * 128 * 8);         // 200,704
  int* cur   = cnt + 50176;                                       // 200,704
  int* eid_s = cur + 50176;                                       // 2 MB
  int* src_s = eid_s + 500224;                                    // 2 MB
  int* dst_s = src_s + 500224;                                    // 2 MB
  int* bsum  = dst_s + 500224;                                    // 1 KB
  unsigned short* x_bf16 = (unsigned short*)(bsum + 256);         // 12.8 MB

  float* out_x = (float*)d_out;
  float* out_e = out_x + (size_t)N * 128;

  // zero num, den, cnt (contiguous)
  hipMemsetAsync(num, 0, (size_t)N * 128 * 8 + 50176 * sizeof(int), stream);
  prep_b_kernel<<<400, 256, 0, stream>>>(Wa, Wt, We, Wee, Bp);
  xbf16_kernel<<<(N * 32 + 255) / 256, 256, 0, stream>>>(x, x_bf16, N * 32);
  hist_kernel<<<(E + 255) / 256, 256, 0, stream>>>(ei, cnt, E);
  scan1_kernel<<<NB, 256, 0, stream>>>(cnt, bsum, N);
  scan2_kernel<<<1, 256, 0, stream>>>(bsum, NB);
  scan3_kernel<<<NB, 256, 0, stream>>>(cnt, bsum, cur, N);
  scatter_kernel<<<(E + 255) / 256, 256, 0, stream>>>(ei, cur, eid_s, src_s,
                                                      dst_s, E);
  fused_edge_kernel<<<(E + 63) / 64, 256, 0, stream>>>(
      x_bf16, ea, eid_s, src_s, dst_s, Bp, num, den, out_e, ap, E);
  finalize_kernel<<<((size_t)N * 128 + 255) / 256, 256, 0, stream>>>(
      num, den, bT, out_x, N * 128);
}